// Round 10
// baseline (86.239 us; speedup 1.0000x reference)
//
#include <hip/hip_runtime.h>
#include <hip/hip_bf16.h>
#include <cstdint>

#define B_ 8
#define N_ 512
#define D_ 256
#define E_ 16384

#define SBK 264    // sB row stride in halfwords (528 B rows, 16B-aligned)
#define NBLK 1024  // 128 blocks per batch

using bf16x8 = __attribute__((ext_vector_type(8))) short;
using f32x4  = __attribute__((ext_vector_type(4))) float;
using f32x2  = __attribute__((ext_vector_type(2))) float;

// HW packed f32->bf16 RNE (v_cvt_pk_bf16_f32). Same rounding as the old
// bit-trick f2bf, but ~1 inst per 2 elements instead of ~10 (m240: compiler
// emits cvt_pk from the cast intrinsics; it cannot pattern-match bit-tricks).
__device__ inline unsigned cvt2u(float lo, float hi) {
    union { __hip_bfloat162 h; unsigned u; } c;
    c.h = __float22bfloat162_rn(make_float2(lo, hi));
    return c.u;
}
__device__ inline unsigned short cvt1u(float f) {
    union { __hip_bfloat16 h; unsigned short s; } c;
    c.h = __float2bfloat16(f);   // RNE
    return c.s;
}

// one bf16x2 dword pair of (u,v): relu(u+v) dot w-pair, packed f32x2 lanes
__device__ inline void pk_step(unsigned ud, unsigned vd, f32x2 wp, f32x2& acc) {
    f32x2 uu, vv;
    uu.x = __uint_as_float(ud << 16); uu.y = __uint_as_float(ud & 0xffff0000u);
    vv.x = __uint_as_float(vd << 16); vv.y = __uint_as_float(vd & 0xffff0000u);
    f32x2 s = uu + vv;
    s = __builtin_elementwise_max(s, (f32x2){0.f, 0.f});
    acc += s * wp;
}

__device__ inline float edge_dot(uint4 u0, uint4 u1, uint4 v0, uint4 v1,
                                 const f32x2* w2p) {
    f32x2 acc = {0.f, 0.f};
    pk_step(u0.x, v0.x, w2p[0], acc);
    pk_step(u0.y, v0.y, w2p[1], acc);
    pk_step(u0.z, v0.z, w2p[2], acc);
    pk_step(u0.w, v0.w, w2p[3], acc);
    pk_step(u1.x, v1.x, w2p[4], acc);
    pk_step(u1.y, v1.y, w2p[5], acc);
    pk_step(u1.z, v1.z, w2p[6], acc);
    pk_step(u1.w, v1.w, w2p[7], acc);
    return acc.x + acc.y;
}

// ONE dispatch, 1024 blocks x 256 threads (4 blocks/CU, 16 waves/CU).
// Identical to R9 except all f32->bf16 conversions use the HW cvt_pk path:
//   - per-batch init-free barrier (8 cnt lines @ ws+b*512, 8 flag lines
//     @ ws+4096+b*512, ref @ ws+8192; all equal to the constant poison dword
//     at start; no memset). Arrival: all-wave vmcnt(0) drain + one
//     fetch_add(cnt). Poll: always-RMW fetch_add(flag,0)+s_sleep(2) (served
//     at the coherence point every iteration -> ~0.1 us exit latency).
//   - spin window: waves 2-3 stage the 128-edge slice while wave 0 polls.
//   - bounded spin; graceful no-op degradation if ws isn't re-poisoned
//     (correct by bit-identical idempotence).
__global__ __launch_bounds__(256, 4)
void fused(const float* __restrict__ feat, const float* __restrict__ W1,
           const float* __restrict__ b1,   const float* __restrict__ W2,
           const float* __restrict__ b2,   const int* __restrict__ eidx,
           unsigned short* __restrict__ P, unsigned* __restrict__ gBar,
           float* __restrict__ out)
{
    __shared__ __align__(16) unsigned short sB[32 * SBK];   // 16896 B
    __shared__ int sES[128], sED[128];                      // +1 KB

    const int bid = blockIdx.x, t = threadIdx.x;
    const int b   = bid & 7;                    // batch == XCD
    const int loc = bid >> 3;                   // 0..127
    const int m0  = b * 512 + (loc >> 4) * 64;  // P row base
    const int bn  = loc & 15;                   // n-tile (16 x 32 cols)
    const int n0  = bn * 32;

    // ---- zero own out slab: batch b, rows loc*4 .. loc*4+3 (8 KB) ----
    {
        float4 z = make_float4(0.f, 0.f, 0.f, 0.f);
        float4* oz = (float4*)(out + ((size_t)b * 512 + (size_t)loc * 4) * 512) + t;
        oz[0] = z; oz[256] = z;
    }

    // ---- B-stage: 32 n-cols x 256 k of W1, transposed into LDS ----
    {
        const int h = bn >> 3, c0 = (bn & 7) * 32;   // W1 half + col base
        const int col = t & 31, kg = t >> 5;          // col, 32-row k-group
        const float* Wp = W1 + ((size_t)(h * 256 + kg * 32)) * 256 + c0 + col;
        unsigned short* dstp = sB + col * SBK + kg * 32;
#pragma unroll
        for (int o = 0; o < 4; o++) {
            float f[8];
#pragma unroll
            for (int j = 0; j < 8; j++)
                f[j] = Wp[(size_t)(o * 8 + j) * 256];
            uint4 q;
            q.x = cvt2u(f[0], f[1]); q.y = cvt2u(f[2], f[3]);
            q.z = cvt2u(f[4], f[5]); q.w = cvt2u(f[6], f[7]);
            *(uint4*)(dstp + o * 8) = q;
        }
    }
    __syncthreads();

    const int wave = t >> 6, lane = t & 63, l15 = lane & 15, quad = lane >> 4;
    {
        // A fragments straight from feat (row-major k-contiguous == MFMA A layout)
        const float* pAw = feat + (size_t)(m0 + wave * 16 + l15) * 256 + quad * 8;
        f32x4 acc[2];
#pragma unroll
        for (int cn = 0; cn < 2; cn++) acc[cn] = (f32x4){0.f, 0.f, 0.f, 0.f};
#pragma unroll
        for (int ks = 0; ks < 8; ks++) {
            float4 lo = *(const float4*)(pAw + ks * 32);
            float4 hi = *(const float4*)(pAw + ks * 32 + 4);
            union { bf16x8 v; unsigned u[4]; } ua;
            ua.u[0] = cvt2u(lo.x, lo.y); ua.u[1] = cvt2u(lo.z, lo.w);
            ua.u[2] = cvt2u(hi.x, hi.y); ua.u[3] = cvt2u(hi.z, hi.w);
            bf16x8 af = ua.v;
#pragma unroll
            for (int cn = 0; cn < 2; cn++) {
                bf16x8 bfr = *(const bf16x8*)(sB + (cn * 16 + l15) * SBK + ks * 32 + quad * 8);
                acc[cn] = __builtin_amdgcn_mfma_f32_16x16x32_bf16(af, bfr, acc[cn], 0, 0, 0);
            }
        }
        // epilogue: P = bf16(acc), b1 folded into U half
#pragma unroll
        for (int cn = 0; cn < 2; cn++) {
            int col = n0 + cn * 16 + l15;
            float bias = (col < 256) ? b1[col] : 0.f;
#pragma unroll
            for (int r = 0; r < 4; r++) {
                int row = m0 + wave * 16 + quad * 4 + r;
                P[(size_t)row * 512 + col] = cvt1u(acc[cn][r] + bias);
            }
        }
    }

    // ---- per-batch barrier ----
    asm volatile("s_waitcnt vmcnt(0)" ::: "memory");   // EVERY wave drains P/out
    __syncthreads();                                   // all drained & present
    {
        unsigned* cnt  = gBar + b * 128;               // ws + b*512B
        unsigned* flag = gBar + 1024 + b * 128;        // ws + 4096 + b*512B
        unsigned* ref  = gBar + 2048;                  // ws + 8192 (never written)
        if (t == 0) {
            unsigned r = __hip_atomic_load(ref, __ATOMIC_RELAXED,
                                           __HIP_MEMORY_SCOPE_AGENT);
            unsigned prev = __hip_atomic_fetch_add(cnt, 1u, __ATOMIC_RELAXED,
                                                   __HIP_MEMORY_SCOPE_AGENT);
            if (prev - r == 127u) {
                __hip_atomic_fetch_add(flag, 1u, __ATOMIC_RELAXED,
                                       __HIP_MEMORY_SCOPE_AGENT);
            } else {
                for (int it = 0; it < (1 << 15); ++it) {
                    unsigned f = __hip_atomic_fetch_add(flag, 0u, __ATOMIC_RELAXED,
                                                        __HIP_MEMORY_SCOPE_AGENT);
                    if (f != r) break;
                    __builtin_amdgcn_s_sleep(2);
                }
            }
            asm volatile("" ::: "memory");
        }
        // spin window: waves 2-3 stage the 128-edge slice while wave 0 polls
        if (t >= 128) {
            int i = t - 128;
            sES[i] = eidx[loc * 128 + i];
            sED[i] = eidx[E_ + loc * 128 + i];
        }
    }
    __syncthreads();   // batch-b P complete + edges staged

    // ---- edge scoring: 16 workers x 8 edges, two 4-edge bursts ----
    {
        const int g = lane >> 4, w = lane & 15;
        const int wid = wave * 4 + g;            // worker 0..15
        const int e0 = wid * 8;                  // local edge base in sES/sED

        f32x2 w2p[8];
#pragma unroll
        for (int j = 0; j < 8; j++) {
            w2p[j].x = W2[w * 16 + 2 * j];
            w2p[j].y = W2[w * 16 + 2 * j + 1];
        }
        const float b2v = b2[0];

        const unsigned short* Pb = P + (size_t)b * 512 * 512;
        float* outb = out + (size_t)b * 512 * 512;

#pragma unroll
        for (int half = 0; half < 2; half++) {
            int ss[4], dd[4];
            uint4 u0[4], u1[4], v0[4], v1[4];
#pragma unroll
            for (int i = 0; i < 4; i++) {
                ss[i] = sES[e0 + half * 4 + i]; dd[i] = sED[e0 + half * 4 + i];
                const unsigned short* pu = Pb + (size_t)ss[i] * 512 + w * 16;
                const unsigned short* pv = Pb + (size_t)dd[i] * 512 + 256 + w * 16;
                u0[i] = *(const uint4*)pu; u1[i] = *(const uint4*)(pu + 8);
                v0[i] = *(const uint4*)pv; v1[i] = *(const uint4*)(pv + 8);
            }
#pragma unroll
            for (int i = 0; i < 4; i++) {
                float p = edge_dot(u0[i], u1[i], v0[i], v1[i], w2p);
                p += __shfl_xor(p, 1);
                p += __shfl_xor(p, 2);
                p += __shfl_xor(p, 4);
                p += __shfl_xor(p, 8);
                if (w == 0)
                    outb[(size_t)ss[i] * 512 + dd[i]] =
                        1.0f / (1.0f + __expf(-(p + b2v)));
            }
        }
    }
}

extern "C" void kernel_launch(void* const* d_in, const int* in_sizes, int n_in,
                              void* d_out, int out_size, void* d_ws, size_t ws_size,
                              hipStream_t stream) {
    const float* feat = (const float*)d_in[0];
    const float* W1   = (const float*)d_in[1];
    const float* b1   = (const float*)d_in[2];
    const float* W2   = (const float*)d_in[3];
    const float* b2   = (const float*)d_in[4];
    const int*   eidx = (const int*)d_in[5];
    float* out = (float*)d_out;

    unsigned* gBar = (unsigned*)d_ws;                              // cnt[8]@0, flag[8]@4096, ref@8192
    unsigned short* P = (unsigned short*)((char*)d_ws + 16384);    // 4 MB

    fused<<<dim3(NBLK), dim3(256), 0, stream>>>(feat, W1, b1, W2, b2, eidx,
                                                P, gBar, out);
}